// Round 2
// baseline (615.925 us; speedup 1.0000x reference)
//
#include <hip/hip_runtime.h>

// ---------------------------------------------------------------------------
// SpatialTransformerPyramid2d fused kernel, round 2.
// N=64, c=32, H=W=128, outdims=4096, SCALE_N=4 (levels hi0..hi3, lo4).
//
// Identities used:
//   sample(hi_{j-1}) = bilin(img_{j-1}) - 4*stencil_{j-1}(lo_j)
//   bilinear taps of level j lie inside the 3-tap stencil support from level
//   j-1, so per level j we read ONE 3x3 patch of lo_j and form two weighted
//   sums (stencil weights "a" for hi_{j-1}, bilinear weights "b" for hi_j).
//   => per (out,ch): 4 global taps (x) + 4 levels * 9 LDS taps.
//
// Block = (n, channel-pair), 512 threads, LDS rows padded +1 to kill
// same-bank different-row conflicts.  44480 B LDS -> 3 blocks/CU,
// 512 thr -> 24 waves/CU (75% occupancy cap).
// ---------------------------------------------------------------------------

#define P1 65
#define P2 33
#define P3 17
#define P4 9
#define OFF_LO1 0                      // 64 rows * 65 = 4160
#define OFF_LO2 4160                   // 32 * 33 = 1056
#define OFF_LO3 5216                   // 16 * 17 = 272
#define OFF_LO4 5488                   // 8 * 9   = 72
#define SLOT    5560                   // floats per channel slot

#define G_A 0.0613609f
#define G_B 0.2447700f
#define G_C 0.3877386f

static __device__ __forceinline__ float clampf(float v, float lo, float hi) {
    return fminf(fmaxf(v, lo), hi);
}
static __device__ __forceinline__ int imin(int a, int b) { return a < b ? a : b; }
static __device__ __forceinline__ int imax(int a, int b) { return a > b ? a : b; }

__global__ void init_out_kernel(const float* __restrict__ bias, float* __restrict__ y) {
    int i = blockIdx.x * blockDim.x + threadIdx.x;
    y[i] = bias[i & 4095];
}

// smooth+downsample one point from an LDS source with row stride `stride`,
// logical size S x S, zero padding outside.
static __device__ __forceinline__ float down_pt_lds(const float* s, int stride, int S,
                                                    int i, int j) {
    const float g1[5] = {G_A, G_B, G_C, G_B, G_A};
    int by = 2 * i - 2, bx = 2 * j - 2;
    float acc = 0.f;
    if (by >= 0 && by + 4 < S && bx >= 0 && bx + 4 < S) {
#pragma unroll
        for (int dy = 0; dy < 5; ++dy) {
            const float* r = s + (by + dy) * stride + bx;
            acc += g1[dy] * (G_A * (r[0] + r[4]) + G_B * (r[1] + r[3]) + G_C * r[2]);
        }
    } else {
#pragma unroll
        for (int dy = 0; dy < 5; ++dy) {
            int yy = by + dy;
            if ((unsigned)yy < (unsigned)S) {
#pragma unroll
                for (int dx = 0; dx < 5; ++dx) {
                    int xx = bx + dx;
                    if ((unsigned)xx < (unsigned)S)
                        acc += g1[dy] * g1[dx] * s[yy * stride + xx];
                }
            }
        }
    }
    return acc;
}

__global__ __launch_bounds__(512, 6) void pyr_sample_kernel(
    const float* __restrict__ x, const float* __restrict__ grid,
    const float* __restrict__ feat, float* __restrict__ y)
{
    __shared__ float s_lo[2 * SLOT];
    const int tid = threadIdx.x;
    const int n   = blockIdx.x >> 4;
    const int c0  = (blockIdx.x & 15) << 1;
    const float* img0 = x + ((size_t)(n * 32 + c0) << 14);

    const float g1[5] = {G_A, G_B, G_C, G_B, G_A};

    // ---- phase 1: lo1 (64x64) per channel, runs of 4 adjacent points ------
    for (int r = tid; r < 2048; r += 512) {
        int gi = r >> 10, p = r & 1023;
        int i = p >> 4, j0 = (p & 15) << 2;
        const float* img = img0 + (gi << 14);
        int by = 2 * i - 2, bx = 2 * j0 - 2;
        float acc[4] = {0.f, 0.f, 0.f, 0.f};
        if (i >= 1 && i <= 62 && j0 >= 4 && j0 <= 56) {
#pragma unroll
            for (int dy = 0; dy < 5; ++dy) {
                const float* row = img + (by + dy) * 128 + bx;
                float v[11];
#pragma unroll
                for (int t = 0; t < 11; ++t) v[t] = row[t];
                float g = g1[dy];
#pragma unroll
                for (int jj = 0; jj < 4; ++jj) {
                    float h = G_A * (v[2 * jj] + v[2 * jj + 4]) +
                              G_B * (v[2 * jj + 1] + v[2 * jj + 3]) +
                              G_C * v[2 * jj + 2];
                    acc[jj] += g * h;
                }
            }
        } else {
#pragma unroll
            for (int dy = 0; dy < 5; ++dy) {
                int yy = by + dy;
                if ((unsigned)yy < 128u) {
#pragma unroll
                    for (int t = 0; t < 11; ++t) {
                        int xx = bx + t;
                        if ((unsigned)xx < 128u) {
                            float v = img[yy * 128 + xx];
#pragma unroll
                            for (int jj = 0; jj < 4; ++jj) {
                                int dx = t - 2 * jj;
                                if (dx >= 0 && dx <= 4) acc[jj] += g1[dy] * g1[dx] * v;
                            }
                        }
                    }
                }
            }
        }
        int base = gi * SLOT + OFF_LO1 + i * P1 + j0;
#pragma unroll
        for (int jj = 0; jj < 4; ++jj) s_lo[base + jj] = acc[jj];
    }
    __syncthreads();

    // ---- phase 2: lo2 (32x32) ----
    for (int pos = tid; pos < 2048; pos += 512) {
        int gi = pos >> 10, p = pos & 1023;
        int i = p >> 5, j = p & 31;
        int b = gi * SLOT;
        s_lo[b + OFF_LO2 + i * P2 + j] = down_pt_lds(s_lo + b + OFF_LO1, P1, 64, i, j);
    }
    __syncthreads();

    // ---- phase 3: lo3 (16x16) ----
    if (tid < 512) {
        int gi = tid >> 8, p = tid & 255;
        int i = p >> 4, j = p & 15;
        int b = gi * SLOT;
        s_lo[b + OFF_LO3 + i * P3 + j] = down_pt_lds(s_lo + b + OFF_LO2, P2, 32, i, j);
    }
    __syncthreads();

    // ---- phase 4: lo4 (8x8) ----
    if (tid < 128) {
        int gi = tid >> 6, p = tid & 63;
        int i = p >> 3, j = p & 7;
        int b = gi * SLOT;
        s_lo[b + OFF_LO4 + i * P4 + j] = down_pt_lds(s_lo + b + OFF_LO3, P3, 16, i, j);
    }
    __syncthreads();

    // ---- phase 5: sample + contract ----
    const float2* g2 = (const float2*)grid;
    for (int out = tid; out < 4096; out += 512) {
        float2 gv = g2[out];
        float xs = clampf(gv.x, -1.f, 1.f);
        float ys = clampf(gv.y, -1.f, 1.f);

        float fA[5], fB[5];
#pragma unroll
        for (int k = 0; k < 5; ++k) {
            fA[k] = feat[((size_t)(k * 32 + c0) << 12) + out];
            fB[k] = feat[((size_t)(k * 32 + c0 + 1) << 12) + out];
        }

        // ---- level 0: bilinear on x (global) ----
        float fx = (xs + 1.f) * 64.f - 0.5f;
        float fy = (ys + 1.f) * 64.f - 0.5f;
        float x0f = floorf(fx), y0f = floorf(fy);
        int x0 = (int)x0f, y0 = (int)y0f;
        float wx = fx - x0f, wy = fy - y0f;
        float ux0 = (x0 >= 0)      ? (1.f - wx) : 0.f;
        float ux1 = (x0 + 1 < 128) ? wx         : 0.f;
        float uy0 = (y0 >= 0)      ? (1.f - wy) : 0.f;
        float uy1 = (y0 + 1 < 128) ? wy         : 0.f;
        int cx0 = imax(x0, 0), cx1 = imin(x0 + 1, 127);
        int cy0 = imax(y0, 0), cy1 = imin(y0 + 1, 127);
        float w00 = ux0 * uy0, w01 = ux1 * uy0, w10 = ux0 * uy1, w11 = ux1 * uy1;

        float acc0, acc1;
        {
            const float* imA = img0;
            const float* imB = img0 + 16384;
            float vA = w00 * imA[cy0 * 128 + cx0] + w01 * imA[cy0 * 128 + cx1] +
                       w10 * imA[cy1 * 128 + cx0] + w11 * imA[cy1 * 128 + cx1];
            float vB = w00 * imB[cy0 * 128 + cx0] + w01 * imB[cy0 * 128 + cx1] +
                       w10 * imB[cy1 * 128 + cx0] + w11 * imB[cy1 * 128 + cx1];
            acc0 = fA[0] * vA;
            acc1 = fB[0] * vB;
        }

        // rolling "previous level" bilinear state
        int   x0p = x0, y0p = y0;
        float ux0p = ux0, ux1p = ux1, uy0p = uy0, uy1p = uy1;

#pragma unroll
        for (int j = 1; j <= 4; ++j) {
            const int Wj  = 128 >> j;
            const int Pj  = (j == 1) ? P1 : (j == 2) ? P2 : (j == 3) ? P3 : P4;
            const int off = (j == 1) ? OFF_LO1 : (j == 2) ? OFF_LO2
                          : (j == 3) ? OFF_LO3 : OFF_LO4;

            // a-weights: -4*up stencil from level j-1 corner pair
            int qx; float ax0, ax1, ax2;
            if (x0p & 1) { qx = (x0p - 1) >> 1;
                ax0 = G_B * ux0p + G_A * ux1p; ax1 = G_B * ux0p + G_C * ux1p; ax2 = G_A * ux1p; }
            else         { qx = (x0p >> 1) - 1;
                ax0 = G_A * ux0p; ax1 = G_C * ux0p + G_B * ux1p; ax2 = G_A * ux0p + G_B * ux1p; }
            int qy; float ay0, ay1, ay2;
            if (y0p & 1) { qy = (y0p - 1) >> 1;
                ay0 = G_B * uy0p + G_A * uy1p; ay1 = G_B * uy0p + G_C * uy1p; ay2 = G_A * uy1p; }
            else         { qy = (y0p >> 1) - 1;
                ay0 = G_A * uy0p; ay1 = G_C * uy0p + G_B * uy1p; ay2 = G_A * uy0p + G_B * uy1p; }

            // level-j bilinear params
            float fxj = (xs + 1.f) * (float)(Wj >> 1) - 0.5f;
            float fyj = (ys + 1.f) * (float)(Wj >> 1) - 0.5f;
            float x0jf = floorf(fxj), y0jf = floorf(fyj);
            int x0j = (int)x0jf, y0j = (int)y0jf;
            float wxj = fxj - x0jf, wyj = fyj - y0jf;
            float ux0j = (x0j >= 0)     ? (1.f - wxj) : 0.f;
            float ux1j = (x0j + 1 < Wj) ? wxj         : 0.f;
            float uy0j = (y0j >= 0)     ? (1.f - wyj) : 0.f;
            float uy1j = (y0j + 1 < Wj) ? wyj         : 0.f;

            // b-weights: level-j bilinear folded into the 3-tap frame
            float bx0 = 0.f, bx1 = 0.f, bx2 = 0.f;
            int posx = imin(imax(x0j - qx, 0), 1);
            if (posx == 0) { bx0 = ux0j; bx1 = ux1j; } else { bx1 = ux0j; bx2 = ux1j; }
            float by0 = 0.f, by1 = 0.f, by2 = 0.f;
            int posy = imin(imax(y0j - qy, 0), 1);
            if (posy == 0) { by0 = uy0j; by1 = uy1j; } else { by1 = uy0j; by2 = uy1j; }

            // tap indices, OOB -> zero weight + clamped index
            int tx[3], ty[3];
            {
                int ix0 = qx, ix1 = qx + 1, ix2 = qx + 2;
                if (ix0 < 0 || ix0 >= Wj) { ax0 = 0.f; bx0 = 0.f; }
                if (ix1 < 0 || ix1 >= Wj) { ax1 = 0.f; bx1 = 0.f; }
                if (ix2 < 0 || ix2 >= Wj) { ax2 = 0.f; bx2 = 0.f; }
                tx[0] = imin(imax(ix0, 0), Wj - 1);
                tx[1] = imin(imax(ix1, 0), Wj - 1);
                tx[2] = imin(imax(ix2, 0), Wj - 1);
                int iy0 = qy, iy1 = qy + 1, iy2 = qy + 2;
                if (iy0 < 0 || iy0 >= Wj) { ay0 = 0.f; by0 = 0.f; }
                if (iy1 < 0 || iy1 >= Wj) { ay1 = 0.f; by1 = 0.f; }
                if (iy2 < 0 || iy2 >= Wj) { ay2 = 0.f; by2 = 0.f; }
                ty[0] = imin(imax(iy0, 0), Wj - 1);
                ty[1] = imin(imax(iy1, 0), Wj - 1);
                ty[2] = imin(imax(iy2, 0), Wj - 1);
            }

#pragma unroll
            for (int gi = 0; gi < 2; ++gi) {
                int pb = gi * SLOT + off;
                int r0 = pb + ty[0] * Pj, r1 = pb + ty[1] * Pj, r2 = pb + ty[2] * Pj;
                float p00 = s_lo[r0 + tx[0]], p01 = s_lo[r0 + tx[1]], p02 = s_lo[r0 + tx[2]];
                float p10 = s_lo[r1 + tx[0]], p11 = s_lo[r1 + tx[1]], p12 = s_lo[r1 + tx[2]];
                float p20 = s_lo[r2 + tx[0]], p21 = s_lo[r2 + tx[1]], p22 = s_lo[r2 + tx[2]];
                float ra0 = ax0 * p00 + ax1 * p01 + ax2 * p02;
                float ra1 = ax0 * p10 + ax1 * p11 + ax2 * p12;
                float ra2 = ax0 * p20 + ax1 * p21 + ax2 * p22;
                float rb0 = bx0 * p00 + bx1 * p01 + bx2 * p02;
                float rb1 = bx0 * p10 + bx1 * p11 + bx2 * p12;
                float rb2 = bx0 * p20 + bx1 * p21 + bx2 * p22;
                float s_a = ay0 * ra0 + ay1 * ra1 + ay2 * ra2;
                float s_b = by0 * rb0 + by1 * rb1 + by2 * rb2;
                float fprev = gi ? fB[j - 1] : fA[j - 1];
                float fcur  = gi ? fB[j]     : fA[j];
                float contrib = fcur * s_b - 4.f * fprev * s_a;
                if (gi == 0) acc0 += contrib; else acc1 += contrib;
            }

            x0p = x0j; y0p = y0j;
            ux0p = ux0j; ux1p = ux1j; uy0p = uy0j; uy1p = uy1j;
        }

        atomicAdd(&y[(n << 12) + out], acc0 + acc1);
    }
}

extern "C" void kernel_launch(void* const* d_in, const int* in_sizes, int n_in,
                              void* d_out, int out_size, void* d_ws, size_t ws_size,
                              hipStream_t stream) {
    (void)in_sizes; (void)n_in; (void)d_ws; (void)ws_size;
    const float* x    = (const float*)d_in[0];
    const float* grid = (const float*)d_in[1];
    const float* feat = (const float*)d_in[2];
    const float* bias = (const float*)d_in[3];
    float* y = (float*)d_out;

    init_out_kernel<<<out_size / 256, 256, 0, stream>>>(bias, y);
    pyr_sample_kernel<<<1024, 512, 0, stream>>>(x, grid, feat, y);
}